// Round 1
// baseline (3542.304 us; speedup 1.0000x reference)
//
#include <hip/hip_runtime.h>

#define N_NODES 100000
#define N_EDGES 3200000
#define D 256

// Static accumulator: agg[r][:] = sum_e val_e * x[col_e][:]  (102.4 MB)
__device__ float g_agg[(size_t)N_NODES * D];

// ---------------------------------------------------------------- zero agg
__global__ void zero_agg_kernel() {
    size_t n4 = (size_t)N_NODES * D / 4;
    float4* p = (float4*)g_agg;
    for (size_t i = (size_t)blockIdx.x * blockDim.x + threadIdx.x; i < n4;
         i += (size_t)gridDim.x * blockDim.x) {
        p[i] = make_float4(0.f, 0.f, 0.f, 0.f);
    }
}

// ---------------------------------------------------------------- SpMM (atomic)
// One 256-thread block processes edges in a grid-stride loop; thread t owns
// feature t. Edge scalars (r,c,v) are block-uniform -> s_load broadcast.
__global__ void spmm_atomic_kernel(const float* __restrict__ x,
                                   const float* __restrict__ edge_val,
                                   const int* __restrict__ edge_row,
                                   const int* __restrict__ edge_col) {
    int t = threadIdx.x;
    for (int e = blockIdx.x; e < N_EDGES; e += gridDim.x) {
        int r = edge_row[e];
        int c = edge_col[e];
        float v = edge_val[e];
        float xv = x[(size_t)c * D + t];
        // native global_atomic_add_f32 (avoids CAS-loop fallback)
        unsafeAtomicAdd(&g_agg[(size_t)r * D + t], v * xv);
    }
}

// ---------------------------------------------------------------- GEMM + ReLU
// out = relu(agg @ W);  agg: [M x 256], W: [256 x 256], out: [M x 256]
// BM=BN=64, BK=16, 256 threads, each thread computes a 4x4 micro-tile.
#define BM 64
#define BN 64
#define BK 16

__launch_bounds__(256)
__global__ void gemm_relu_kernel(const float* __restrict__ W,
                                 float* __restrict__ out) {
    __shared__ __align__(16) float As[BK][BM + 4];  // stride 68: A-tile transposed
    __shared__ __align__(16) float Bs[BK][BN + 4];

    const float* A = g_agg;
    const int tid = threadIdx.x;
    const int tx = tid & 15;        // micro-tile col group
    const int ty = tid >> 4;        // micro-tile row group
    const int rowBase = blockIdx.x * BM;
    const int colBase = blockIdx.y * BN;

    // loader indexing
    const int la_row = tid >> 2;          // 0..63 (A-tile row)
    const int la_k   = (tid & 3) * 4;     // 0,4,8,12 (A-tile k quad)
    const int lb_row = tid >> 4;          // 0..15 (B-tile k row)
    const int lb_c   = (tid & 15) * 4;    // 0..60 (B-tile col quad)

    float acc[4][4] = {};

    for (int k0 = 0; k0 < D; k0 += BK) {
        // ---- stage A tile (transposed into LDS)
        int ar = rowBase + la_row;
        float4 av = make_float4(0.f, 0.f, 0.f, 0.f);
        if (ar < N_NODES)
            av = *(const float4*)&A[(size_t)ar * D + (k0 + la_k)];
        As[la_k + 0][la_row] = av.x;
        As[la_k + 1][la_row] = av.y;
        As[la_k + 2][la_row] = av.z;
        As[la_k + 3][la_row] = av.w;
        // ---- stage B tile
        float4 bv = *(const float4*)&W[(size_t)(k0 + lb_row) * D + (colBase + lb_c)];
        *(float4*)&Bs[lb_row][lb_c] = bv;
        __syncthreads();

        #pragma unroll
        for (int kk = 0; kk < BK; ++kk) {
            float4 a = *(const float4*)&As[kk][ty * 4];
            float4 b = *(const float4*)&Bs[kk][tx * 4];
            acc[0][0] += a.x * b.x; acc[0][1] += a.x * b.y; acc[0][2] += a.x * b.z; acc[0][3] += a.x * b.w;
            acc[1][0] += a.y * b.x; acc[1][1] += a.y * b.y; acc[1][2] += a.y * b.z; acc[1][3] += a.y * b.w;
            acc[2][0] += a.z * b.x; acc[2][1] += a.z * b.y; acc[2][2] += a.z * b.z; acc[2][3] += a.z * b.w;
            acc[3][0] += a.w * b.x; acc[3][1] += a.w * b.y; acc[3][2] += a.w * b.z; acc[3][3] += a.w * b.w;
        }
        __syncthreads();
    }

    // ---- epilogue: ReLU + store
    #pragma unroll
    for (int i = 0; i < 4; ++i) {
        int row = rowBase + ty * 4 + i;
        if (row < N_NODES) {
            float4 o;
            o.x = fmaxf(acc[i][0], 0.f);
            o.y = fmaxf(acc[i][1], 0.f);
            o.z = fmaxf(acc[i][2], 0.f);
            o.w = fmaxf(acc[i][3], 0.f);
            *(float4*)&out[(size_t)row * D + (colBase + tx * 4)] = o;
        }
    }
}

// ---------------------------------------------------------------- launcher
extern "C" void kernel_launch(void* const* d_in, const int* in_sizes, int n_in,
                              void* d_out, int out_size, void* d_ws, size_t ws_size,
                              hipStream_t stream) {
    const float* x        = (const float*)d_in[0];
    const float* weight   = (const float*)d_in[1];
    const float* edge_val = (const float*)d_in[2];
    const int*   edge_row = (const int*)d_in[3];
    const int*   edge_col = (const int*)d_in[4];
    float* out = (float*)d_out;

    // 1) zero the aggregation buffer (25.6M floats / 4 = 6.4M float4)
    zero_agg_kernel<<<25000, 256, 0, stream>>>();

    // 2) sparse aggregation: agg[r] += val * x[c]
    spmm_atomic_kernel<<<32768, 256, 0, stream>>>(x, edge_val, edge_row, edge_col);

    // 3) dense GEMM + ReLU: out = relu(agg @ W)
    dim3 grid((N_NODES + BM - 1) / BM, D / BN);  // 1563 x 4
    gemm_relu_kernel<<<grid, 256, 0, stream>>>(weight, out);
}

// Round 2
// 1430.624 us; speedup vs baseline: 2.4761x; 2.4761x over previous
//
#include <hip/hip_runtime.h>

#define N_NODES 100000
#define N_EDGES 3200000
#define D 256

// ---------------- static device scratch (re-built every call) ----------------
__device__ float g_agg[(size_t)N_NODES * D];   // 102.4 MB aggregation result
__device__ int   g_counts[N_NODES];            // per-row edge counts
__device__ int   g_row_start[N_NODES + 1];     // CSR offsets
__device__ int   g_cursor[N_NODES];            // scatter cursors
__device__ int   g_col_s[N_EDGES];             // edge cols, sorted by row
__device__ float g_val_s[N_EDGES];             // edge vals, sorted by row

// ---------------------------------------------------------------- zero counts
__global__ void zero_counts_kernel() {
    for (int i = blockIdx.x * blockDim.x + threadIdx.x; i < N_NODES;
         i += gridDim.x * blockDim.x)
        g_counts[i] = 0;
}

// ---------------------------------------------------------------- histogram
__global__ void hist_kernel(const int* __restrict__ edge_row) {
    for (int e = blockIdx.x * blockDim.x + threadIdx.x; e < N_EDGES;
         e += gridDim.x * blockDim.x)
        atomicAdd(&g_counts[edge_row[e]], 1);
}

// ---------------------------------------------------------------- scan (1 block)
// Exclusive prefix sum over g_counts -> g_row_start & g_cursor.
#define SCAN_T 1024
__global__ void scan_kernel() {
    __shared__ int s[SCAN_T];
    const int tid = threadIdx.x;
    const int chunk = (N_NODES + SCAN_T - 1) / SCAN_T;  // 98
    const int base = tid * chunk;

    int sum = 0;
    for (int j = 0; j < chunk; ++j) {
        int idx = base + j;
        if (idx < N_NODES) sum += g_counts[idx];
    }
    s[tid] = sum;
    __syncthreads();
    // Hillis-Steele inclusive scan over 1024 partials
    for (int off = 1; off < SCAN_T; off <<= 1) {
        int v = s[tid];
        if (tid >= off) v += s[tid - off];
        __syncthreads();
        s[tid] = v;
        __syncthreads();
    }
    int running = (tid == 0) ? 0 : s[tid - 1];
    for (int j = 0; j < chunk; ++j) {
        int idx = base + j;
        if (idx < N_NODES) {
            g_row_start[idx] = running;
            g_cursor[idx]    = running;
            running += g_counts[idx];
        }
    }
    if (tid == SCAN_T - 1) g_row_start[N_NODES] = s[SCAN_T - 1];
}

// ---------------------------------------------------------------- scatter
__global__ void scatter_kernel(const float* __restrict__ edge_val,
                               const int* __restrict__ edge_row,
                               const int* __restrict__ edge_col) {
    for (int e = blockIdx.x * blockDim.x + threadIdx.x; e < N_EDGES;
         e += gridDim.x * blockDim.x) {
        int r = edge_row[e];
        int pos = atomicAdd(&g_cursor[r], 1);
        g_col_s[pos] = edge_col[e];
        g_val_s[pos] = edge_val[e];
    }
}

// ---------------------------------------------------------------- CSR SpMM
// One block per row; thread t owns feature t. Register accumulation,
// single plain store per element — zero global atomics.
__launch_bounds__(256)
__global__ void spmm_csr_kernel(const float* __restrict__ x) {
    const int r = blockIdx.x;
    const int t = threadIdx.x;
    const int s = g_row_start[r];
    const int e = g_row_start[r + 1];

    float acc = 0.f;
    int i = s;
    for (; i + 1 < e; i += 2) {               // unroll 2 for MLP
        int   c0 = g_col_s[i],     c1 = g_col_s[i + 1];
        float v0 = g_val_s[i],     v1 = g_val_s[i + 1];
        float x0 = x[(size_t)c0 * D + t];
        float x1 = x[(size_t)c1 * D + t];
        acc += v0 * x0;
        acc += v1 * x1;
    }
    if (i < e) {
        int   c = g_col_s[i];
        float v = g_val_s[i];
        acc += v * x[(size_t)c * D + t];
    }
    g_agg[(size_t)r * D + t] = acc;
}

// ---------------------------------------------------------------- GEMM + ReLU
// out = relu(agg @ W);  agg: [M x 256], W: [256 x 256]
#define BM 64
#define BN 64
#define BK 16

__launch_bounds__(256)
__global__ void gemm_relu_kernel(const float* __restrict__ W,
                                 float* __restrict__ out) {
    __shared__ __align__(16) float As[BK][BM + 4];
    __shared__ __align__(16) float Bs[BK][BN + 4];

    const float* A = g_agg;
    const int tid = threadIdx.x;
    const int tx = tid & 15;
    const int ty = tid >> 4;
    const int rowBase = blockIdx.x * BM;
    const int colBase = blockIdx.y * BN;

    const int la_row = tid >> 2;
    const int la_k   = (tid & 3) * 4;
    const int lb_row = tid >> 4;
    const int lb_c   = (tid & 15) * 4;

    float acc[4][4] = {};

    for (int k0 = 0; k0 < D; k0 += BK) {
        int ar = rowBase + la_row;
        float4 av = make_float4(0.f, 0.f, 0.f, 0.f);
        if (ar < N_NODES)
            av = *(const float4*)&A[(size_t)ar * D + (k0 + la_k)];
        As[la_k + 0][la_row] = av.x;
        As[la_k + 1][la_row] = av.y;
        As[la_k + 2][la_row] = av.z;
        As[la_k + 3][la_row] = av.w;
        float4 bv = *(const float4*)&W[(size_t)(k0 + lb_row) * D + (colBase + lb_c)];
        *(float4*)&Bs[lb_row][lb_c] = bv;
        __syncthreads();

        #pragma unroll
        for (int kk = 0; kk < BK; ++kk) {
            float4 a = *(const float4*)&As[kk][ty * 4];
            float4 b = *(const float4*)&Bs[kk][tx * 4];
            acc[0][0] += a.x * b.x; acc[0][1] += a.x * b.y; acc[0][2] += a.x * b.z; acc[0][3] += a.x * b.w;
            acc[1][0] += a.y * b.x; acc[1][1] += a.y * b.y; acc[1][2] += a.y * b.z; acc[1][3] += a.y * b.w;
            acc[2][0] += a.z * b.x; acc[2][1] += a.z * b.y; acc[2][2] += a.z * b.z; acc[2][3] += a.z * b.w;
            acc[3][0] += a.w * b.x; acc[3][1] += a.w * b.y; acc[3][2] += a.w * b.z; acc[3][3] += a.w * b.w;
        }
        __syncthreads();
    }

    #pragma unroll
    for (int i = 0; i < 4; ++i) {
        int row = rowBase + ty * 4 + i;
        if (row < N_NODES) {
            float4 o;
            o.x = fmaxf(acc[i][0], 0.f);
            o.y = fmaxf(acc[i][1], 0.f);
            o.z = fmaxf(acc[i][2], 0.f);
            o.w = fmaxf(acc[i][3], 0.f);
            *(float4*)&out[(size_t)row * D + (colBase + tx * 4)] = o;
        }
    }
}

// ---------------------------------------------------------------- launcher
extern "C" void kernel_launch(void* const* d_in, const int* in_sizes, int n_in,
                              void* d_out, int out_size, void* d_ws, size_t ws_size,
                              hipStream_t stream) {
    const float* x        = (const float*)d_in[0];
    const float* weight   = (const float*)d_in[1];
    const float* edge_val = (const float*)d_in[2];
    const int*   edge_row = (const int*)d_in[3];
    const int*   edge_col = (const int*)d_in[4];
    float* out = (float*)d_out;

    // build CSR (counting sort by destination row)
    zero_counts_kernel<<<128, 256, 0, stream>>>();
    hist_kernel<<<2048, 256, 0, stream>>>(edge_row);
    scan_kernel<<<1, SCAN_T, 0, stream>>>();
    scatter_kernel<<<2048, 256, 0, stream>>>(edge_val, edge_row, edge_col);

    // aggregate: agg[r] = sum val * x[c]   (register accumulation, no atomics)
    spmm_csr_kernel<<<N_NODES, 256, 0, stream>>>(x);

    // out = relu(agg @ W)
    dim3 grid((N_NODES + BM - 1) / BM, D / BN);
    gemm_relu_kernel<<<grid, 256, 0, stream>>>(weight, out);
}

// Round 3
// 1263.979 us; speedup vs baseline: 2.8025x; 1.1318x over previous
//
#include <hip/hip_runtime.h>

#define N_NODES 100000
#define N_EDGES 3200000
#define D 256

typedef __attribute__((ext_vector_type(8))) short bf16x8;
typedef __attribute__((ext_vector_type(4))) float f32x4;

// ---------------- static device scratch (rebuilt every call) ----------------
__device__ unsigned short g_x_bf16[(size_t)N_NODES * D];    // 51.2 MB
__device__ unsigned short g_wt[(size_t)D * D];              // W^T bf16, [n][k]
__device__ unsigned short g_support[(size_t)N_NODES * D];   // 51.2 MB bf16
__device__ int   g_counts[N_NODES];
__device__ int   g_row_start[N_NODES + 1];
__device__ int   g_cursor[N_NODES];
__device__ int2  g_edge_s[N_EDGES];                         // {col, val bits}

// fp32 -> bf16 round-to-nearest-even
__device__ __forceinline__ unsigned short f2bf(float f) {
    unsigned u = __float_as_uint(f);
    unsigned r = u + 0x7fffu + ((u >> 16) & 1u);
    return (unsigned short)(r >> 16);
}

// ---------------------------------------------------------------- convert x
__global__ void convert_x_kernel(const float* __restrict__ x) {
    size_t i = ((size_t)blockIdx.x * blockDim.x + threadIdx.x) * 4;
    size_t stride = (size_t)gridDim.x * blockDim.x * 4;
    for (; i < (size_t)N_NODES * D; i += stride) {
        float4 v = *(const float4*)&x[i];
        ushort4 o;
        o.x = f2bf(v.x); o.y = f2bf(v.y); o.z = f2bf(v.z); o.w = f2bf(v.w);
        *(ushort4*)&g_x_bf16[i] = o;
    }
}

// ---------------------------------------------------------------- convert W^T
__global__ void convert_wt_kernel(const float* __restrict__ W) {
    int n = threadIdx.x;  // 0..255 — output row n of W^T
    for (int k = 0; k < D; ++k)
        g_wt[(size_t)n * D + k] = f2bf(W[(size_t)k * D + n]);
}

// ---------------------------------------------------------------- CSR build
__global__ void zero_counts_kernel() {
    for (int i = blockIdx.x * blockDim.x + threadIdx.x; i < N_NODES;
         i += gridDim.x * blockDim.x)
        g_counts[i] = 0;
}

__global__ void hist_kernel(const int* __restrict__ edge_row) {
    for (int e = blockIdx.x * blockDim.x + threadIdx.x; e < N_EDGES;
         e += gridDim.x * blockDim.x)
        atomicAdd(&g_counts[edge_row[e]], 1);
}

#define SCAN_T 1024
__global__ void scan_kernel() {
    __shared__ int s[SCAN_T];
    const int tid = threadIdx.x;
    const int chunk = (N_NODES + SCAN_T - 1) / SCAN_T;  // 98
    const int base = tid * chunk;

    int sum = 0;
    for (int j = 0; j < chunk; ++j) {
        int idx = base + j;
        if (idx < N_NODES) sum += g_counts[idx];
    }
    s[tid] = sum;
    __syncthreads();
    for (int off = 1; off < SCAN_T; off <<= 1) {
        int v = s[tid];
        if (tid >= off) v += s[tid - off];
        __syncthreads();
        s[tid] = v;
        __syncthreads();
    }
    int running = (tid == 0) ? 0 : s[tid - 1];
    for (int j = 0; j < chunk; ++j) {
        int idx = base + j;
        if (idx < N_NODES) {
            g_row_start[idx] = running;
            g_cursor[idx]    = running;
            running += g_counts[idx];
        }
    }
    if (tid == SCAN_T - 1) g_row_start[N_NODES] = s[SCAN_T - 1];
}

__global__ void scatter_kernel(const float* __restrict__ edge_val,
                               const int* __restrict__ edge_row,
                               const int* __restrict__ edge_col) {
    for (int e = blockIdx.x * blockDim.x + threadIdx.x; e < N_EDGES;
         e += gridDim.x * blockDim.x) {
        int r = edge_row[e];
        int pos = atomicAdd(&g_cursor[r], 1);
        int2 pk;
        pk.x = edge_col[e];
        pk.y = __float_as_int(edge_val[e]);
        g_edge_s[pos] = pk;   // single 8 B scattered store
    }
}

// ---------------------------------------------------------------- MFMA GEMM
// support = bf16(x_bf16 @ W) ; per-wave 16x64 output tile, K=256.
__launch_bounds__(256)
__global__ void gemm_mfma_kernel() {
    const int tid  = threadIdx.x;
    const int wave = tid >> 6;
    const int lane = tid & 63;
    const int m0   = blockIdx.x * 16;       // 6250 blocks, M=100000 exact
    const int n0   = wave * 64;
    const int lm   = lane & 15;
    const int q    = lane >> 4;             // quad 0..3

    const unsigned short* A = g_x_bf16;
    const unsigned short* B = g_wt;

    f32x4 acc0 = {}, acc1 = {}, acc2 = {}, acc3 = {};

    #pragma unroll
    for (int k0 = 0; k0 < D; k0 += 32) {
        // A frag: A[m=lm][k=q*8+j] — 16 B contiguous load
        bf16x8 a = *(const bf16x8*)&A[(size_t)(m0 + lm) * D + k0 + q * 8];
        // B frags from W^T (N-major): B[k=q*8+j][n=lm] — 16 B contiguous
        bf16x8 b0 = *(const bf16x8*)&B[(size_t)(n0 +  0 + lm) * D + k0 + q * 8];
        bf16x8 b1 = *(const bf16x8*)&B[(size_t)(n0 + 16 + lm) * D + k0 + q * 8];
        bf16x8 b2 = *(const bf16x8*)&B[(size_t)(n0 + 32 + lm) * D + k0 + q * 8];
        bf16x8 b3 = *(const bf16x8*)&B[(size_t)(n0 + 48 + lm) * D + k0 + q * 8];
        acc0 = __builtin_amdgcn_mfma_f32_16x16x32_bf16(a, b0, acc0, 0, 0, 0);
        acc1 = __builtin_amdgcn_mfma_f32_16x16x32_bf16(a, b1, acc1, 0, 0, 0);
        acc2 = __builtin_amdgcn_mfma_f32_16x16x32_bf16(a, b2, acc2, 0, 0, 0);
        acc3 = __builtin_amdgcn_mfma_f32_16x16x32_bf16(a, b3, acc3, 0, 0, 0);
    }

    // epilogue: C/D layout col=lane&15, row=q*4+reg — stage through LDS
    __shared__ float tile[4][16][68];
    #pragma unroll
    for (int r = 0; r < 4; ++r) {
        tile[wave][q * 4 + r][ 0 + lm] = acc0[r];
        tile[wave][q * 4 + r][16 + lm] = acc1[r];
        tile[wave][q * 4 + r][32 + lm] = acc2[r];
        tile[wave][q * 4 + r][48 + lm] = acc3[r];
    }
    // same wave produces & consumes — lgkmcnt ordering suffices, no barrier
    const int row  = lane >> 2;        // 0..15
    const int cseg = (lane & 3) * 16;  // 0,16,32,48
    unsigned short outv[16];
    #pragma unroll
    for (int j = 0; j < 16; ++j)
        outv[j] = f2bf(tile[wave][row][cseg + j]);
    unsigned short* dst = &g_support[(size_t)(m0 + row) * D + n0 + cseg];
    *(uint4*)&dst[0] = *(const uint4*)&outv[0];   // 16 B
    *(uint4*)&dst[8] = *(const uint4*)&outv[8];   // 16 B
}

// ---------------------------------------------------------------- CSR SpMM
// One 128-thread block per row; thread t owns features 2t, 2t+1 (one uint).
// out[r] = relu( sum_e val_e * support[col_e] )
__launch_bounds__(128)
__global__ void spmm_csr_kernel(float* __restrict__ out) {
    const int r = blockIdx.x;
    const int t = threadIdx.x;
    const int s = g_row_start[r];
    const int e = g_row_start[r + 1];

    const unsigned* sup = (const unsigned*)g_support;  // bf16x2 per uint
    float a0 = 0.f, a1 = 0.f;
    int i = s;
    for (; i + 1 < e; i += 2) {
        int2 e0 = g_edge_s[i];
        int2 e1 = g_edge_s[i + 1];
        float v0 = __int_as_float(e0.y);
        float v1 = __int_as_float(e1.y);
        unsigned p0 = sup[(size_t)e0.x * (D / 2) + t];
        unsigned p1 = sup[(size_t)e1.x * (D / 2) + t];
        a0 += v0 * __uint_as_float(p0 << 16);
        a1 += v0 * __uint_as_float(p0 & 0xffff0000u);
        a0 += v1 * __uint_as_float(p1 << 16);
        a1 += v1 * __uint_as_float(p1 & 0xffff0000u);
    }
    if (i < e) {
        int2 e0 = g_edge_s[i];
        float v0 = __int_as_float(e0.y);
        unsigned p0 = sup[(size_t)e0.x * (D / 2) + t];
        a0 += v0 * __uint_as_float(p0 << 16);
        a1 += v0 * __uint_as_float(p0 & 0xffff0000u);
    }
    float2 o;
    o.x = fmaxf(a0, 0.f);
    o.y = fmaxf(a1, 0.f);
    *(float2*)&out[(size_t)r * D + 2 * t] = o;
}

// ---------------------------------------------------------------- launcher
extern "C" void kernel_launch(void* const* d_in, const int* in_sizes, int n_in,
                              void* d_out, int out_size, void* d_ws, size_t ws_size,
                              hipStream_t stream) {
    const float* x        = (const float*)d_in[0];
    const float* weight   = (const float*)d_in[1];
    const float* edge_val = (const float*)d_in[2];
    const int*   edge_row = (const int*)d_in[3];
    const int*   edge_col = (const int*)d_in[4];
    float* out = (float*)d_out;

    // dtype converts
    convert_x_kernel<<<12800, 256, 0, stream>>>(x);
    convert_wt_kernel<<<1, 256, 0, stream>>>(weight);

    // CSR build (counting sort by destination row)
    zero_counts_kernel<<<128, 256, 0, stream>>>();
    hist_kernel<<<2048, 256, 0, stream>>>(edge_row);
    scan_kernel<<<1, SCAN_T, 0, stream>>>();
    scatter_kernel<<<2048, 256, 0, stream>>>(edge_val, edge_row, edge_col);

    // support = bf16(x @ W) via MFMA
    gemm_mfma_kernel<<<N_NODES / 16, 256, 0, stream>>>();

    // out = relu(A_sp @ support)
    spmm_csr_kernel<<<N_NODES, 128, 0, stream>>>(out);
}

// Round 4
// 763.113 us; speedup vs baseline: 4.6419x; 1.6563x over previous
//
#include <hip/hip_runtime.h>

#define N_NODES 100000
#define N_EDGES 3200000
#define D 256
#define CAP 96          // padded-CSR row capacity (mean deg 32; P(deg>=96) ~ 1e-18)
#define OVF_MAX 4096

typedef __attribute__((ext_vector_type(8))) short bf16x8;
typedef __attribute__((ext_vector_type(4))) float f32x4;

// ---------------- static device scratch (rebuilt every call) ----------------
__device__ unsigned short g_x_bf16[(size_t)N_NODES * D];    // 51.2 MB
__device__ unsigned short g_wt[(size_t)D * D];              // W^T bf16 [n][k]
__device__ unsigned short g_support[(size_t)N_NODES * D];   // 51.2 MB bf16
__device__ int   g_cursor[N_NODES];                         // per-row degree
__device__ int2  g_pad[(size_t)N_NODES * CAP];              // 76.8 MB {col, val}
__device__ int   g_novf;
__device__ int   g_ovf_row[OVF_MAX];
__device__ int2  g_ovf_edge[OVF_MAX];

// fp32 -> bf16 round-to-nearest-even
__device__ __forceinline__ unsigned short f2bf(float f) {
    unsigned u = __float_as_uint(f);
    unsigned r = u + 0x7fffu + ((u >> 16) & 1u);
    return (unsigned short)(r >> 16);
}

// --------------------------------------------- convert x -> bf16, zero cursors
__global__ void convert_x_zero_kernel(const float* __restrict__ x) {
    size_t tid0 = (size_t)blockIdx.x * blockDim.x + threadIdx.x;
    // fused: zero cursors + overflow count
    for (size_t i = tid0; i < N_NODES; i += (size_t)gridDim.x * blockDim.x)
        g_cursor[i] = 0;
    if (tid0 == 0) g_novf = 0;

    size_t i = tid0 * 4;
    size_t stride = (size_t)gridDim.x * blockDim.x * 4;
    for (; i < (size_t)N_NODES * D; i += stride) {
        float4 v = *(const float4*)&x[i];
        ushort4 o;
        o.x = f2bf(v.x); o.y = f2bf(v.y); o.z = f2bf(v.z); o.w = f2bf(v.w);
        *(ushort4*)&g_x_bf16[i] = o;
    }
}

// ---------------------------------------------------------------- convert W^T
__global__ void convert_wt_kernel(const float* __restrict__ W) {
    int n = threadIdx.x;                  // 0..255
    int k0 = blockIdx.x * 4;              // 64 blocks x 4 k's
    #pragma unroll
    for (int j = 0; j < 4; ++j) {
        int k = k0 + j;
        g_wt[(size_t)n * D + k] = f2bf(W[(size_t)k * D + n]);
    }
}

// ------------------------------------------------- scatter into padded CSR
__global__ void scatter_kernel(const float* __restrict__ edge_val,
                               const int* __restrict__ edge_row,
                               const int* __restrict__ edge_col) {
    for (int e = blockIdx.x * blockDim.x + threadIdx.x; e < N_EDGES;
         e += gridDim.x * blockDim.x) {
        int r = edge_row[e];
        int slot = atomicAdd(&g_cursor[r], 1);
        int2 pk;
        pk.x = edge_col[e];
        pk.y = __float_as_int(edge_val[e]);
        if (slot < CAP) {
            g_pad[(size_t)r * CAP + slot] = pk;    // one 8 B scattered store
        } else {
            int o = atomicAdd(&g_novf, 1);
            if (o < OVF_MAX) { g_ovf_row[o] = r; g_ovf_edge[o] = pk; }
        }
    }
}

// ---------------------------------------------------------------- MFMA GEMM
// support = bf16(x_bf16 @ W); per-wave 16x64 tile, K=256.
__launch_bounds__(256)
__global__ void gemm_mfma_kernel() {
    const int tid  = threadIdx.x;
    const int wave = tid >> 6;
    const int lane = tid & 63;
    const int m0   = blockIdx.x * 16;
    const int n0   = wave * 64;
    const int lm   = lane & 15;
    const int q    = lane >> 4;

    const unsigned short* A = g_x_bf16;
    const unsigned short* B = g_wt;

    f32x4 acc0 = {}, acc1 = {}, acc2 = {}, acc3 = {};

    #pragma unroll
    for (int k0 = 0; k0 < D; k0 += 32) {
        bf16x8 a  = *(const bf16x8*)&A[(size_t)(m0 + lm) * D + k0 + q * 8];
        bf16x8 b0 = *(const bf16x8*)&B[(size_t)(n0 +  0 + lm) * D + k0 + q * 8];
        bf16x8 b1 = *(const bf16x8*)&B[(size_t)(n0 + 16 + lm) * D + k0 + q * 8];
        bf16x8 b2 = *(const bf16x8*)&B[(size_t)(n0 + 32 + lm) * D + k0 + q * 8];
        bf16x8 b3 = *(const bf16x8*)&B[(size_t)(n0 + 48 + lm) * D + k0 + q * 8];
        acc0 = __builtin_amdgcn_mfma_f32_16x16x32_bf16(a, b0, acc0, 0, 0, 0);
        acc1 = __builtin_amdgcn_mfma_f32_16x16x32_bf16(a, b1, acc1, 0, 0, 0);
        acc2 = __builtin_amdgcn_mfma_f32_16x16x32_bf16(a, b2, acc2, 0, 0, 0);
        acc3 = __builtin_amdgcn_mfma_f32_16x16x32_bf16(a, b3, acc3, 0, 0, 0);
    }

    __shared__ float tile[4][16][68];
    #pragma unroll
    for (int r = 0; r < 4; ++r) {
        tile[wave][q * 4 + r][ 0 + lm] = acc0[r];
        tile[wave][q * 4 + r][16 + lm] = acc1[r];
        tile[wave][q * 4 + r][32 + lm] = acc2[r];
        tile[wave][q * 4 + r][48 + lm] = acc3[r];
    }
    const int row  = lane >> 2;
    const int cseg = (lane & 3) * 16;
    unsigned short outv[16];
    #pragma unroll
    for (int j = 0; j < 16; ++j)
        outv[j] = f2bf(tile[wave][row][cseg + j]);
    unsigned short* dst = &g_support[(size_t)(m0 + row) * D + n0 + cseg];
    *(uint4*)&dst[0] = *(const uint4*)&outv[0];
    *(uint4*)&dst[8] = *(const uint4*)&outv[8];
}

// ---------------------------------------------------------------- SpMM
// One 128-thread block per row; thread t owns features 2t, 2t+1.
__launch_bounds__(128)
__global__ void spmm_kernel(float* __restrict__ out) {
    const int r = blockIdx.x;
    const int t = threadIdx.x;
    const int deg = g_cursor[r];
    const int dpad = min(deg, CAP);
    const int2* rowp = &g_pad[(size_t)r * CAP];
    const unsigned* sup = (const unsigned*)g_support;

    float a0 = 0.f, a1 = 0.f;
    int i = 0;
    for (; i + 3 < dpad; i += 4) {
        int2 e0 = rowp[i], e1 = rowp[i + 1], e2 = rowp[i + 2], e3 = rowp[i + 3];
        unsigned p0 = sup[(size_t)e0.x * (D / 2) + t];
        unsigned p1 = sup[(size_t)e1.x * (D / 2) + t];
        unsigned p2 = sup[(size_t)e2.x * (D / 2) + t];
        unsigned p3 = sup[(size_t)e3.x * (D / 2) + t];
        float v0 = __int_as_float(e0.y), v1 = __int_as_float(e1.y);
        float v2 = __int_as_float(e2.y), v3 = __int_as_float(e3.y);
        a0 += v0 * __uint_as_float(p0 << 16);
        a1 += v0 * __uint_as_float(p0 & 0xffff0000u);
        a0 += v1 * __uint_as_float(p1 << 16);
        a1 += v1 * __uint_as_float(p1 & 0xffff0000u);
        a0 += v2 * __uint_as_float(p2 << 16);
        a1 += v2 * __uint_as_float(p2 & 0xffff0000u);
        a0 += v3 * __uint_as_float(p3 << 16);
        a1 += v3 * __uint_as_float(p3 & 0xffff0000u);
    }
    for (; i < dpad; ++i) {
        int2 e0 = rowp[i];
        float v0 = __int_as_float(e0.y);
        unsigned p0 = sup[(size_t)e0.x * (D / 2) + t];
        a0 += v0 * __uint_as_float(p0 << 16);
        a1 += v0 * __uint_as_float(p0 & 0xffff0000u);
    }
    if (deg > CAP) {                       // correctness fallback (empty in practice)
        int novf = min(g_novf, OVF_MAX);
        for (int j = 0; j < novf; ++j) {
            if (g_ovf_row[j] == r) {
                int2 e0 = g_ovf_edge[j];
                float v0 = __int_as_float(e0.y);
                unsigned p0 = sup[(size_t)e0.x * (D / 2) + t];
                a0 += v0 * __uint_as_float(p0 << 16);
                a1 += v0 * __uint_as_float(p0 & 0xffff0000u);
            }
        }
    }
    float2 o;
    o.x = fmaxf(a0, 0.f);
    o.y = fmaxf(a1, 0.f);
    *(float2*)&out[(size_t)r * D + 2 * t] = o;
}

// ---------------------------------------------------------------- launcher
extern "C" void kernel_launch(void* const* d_in, const int* in_sizes, int n_in,
                              void* d_out, int out_size, void* d_ws, size_t ws_size,
                              hipStream_t stream) {
    const float* x        = (const float*)d_in[0];
    const float* weight   = (const float*)d_in[1];
    const float* edge_val = (const float*)d_in[2];
    const int*   edge_row = (const int*)d_in[3];
    const int*   edge_col = (const int*)d_in[4];
    float* out = (float*)d_out;

    convert_x_zero_kernel<<<12800, 256, 0, stream>>>(x);
    convert_wt_kernel<<<64, 256, 0, stream>>>(weight);
    scatter_kernel<<<2048, 256, 0, stream>>>(edge_val, edge_row, edge_col);
    gemm_mfma_kernel<<<N_NODES / 16, 256, 0, stream>>>();
    spmm_kernel<<<N_NODES, 128, 0, stream>>>(out);
}

// Round 5
// 730.612 us; speedup vs baseline: 4.8484x; 1.0445x over previous
//
#include <hip/hip_runtime.h>

#define N_NODES 100000
#define N_EDGES 3200000
#define D 256
#define CAP 96          // padded-CSR row capacity (mean deg 32; P(deg>=96) ~ 1e-18)
#define OVF_MAX 4096

#define GEMM_BLOCKS (N_NODES / 16)   // 6250
#define SCAT_BLOCKS 2048

typedef __attribute__((ext_vector_type(8))) short bf16x8;
typedef __attribute__((ext_vector_type(4))) float f32x4;
typedef __attribute__((ext_vector_type(2))) float f32x2;

// ---------------- static device scratch (rebuilt every call) ----------------
__device__ unsigned short g_wt[(size_t)D * D];              // W^T bf16 [n][k]
__device__ unsigned short g_support[(size_t)N_NODES * D];   // 51.2 MB bf16
__device__ int   g_cursor[N_NODES];                         // per-row degree
__device__ int2  g_pad[(size_t)N_NODES * CAP];              // 76.8 MB {col, val}
__device__ int   g_novf;
__device__ int   g_ovf_row[OVF_MAX];
__device__ int2  g_ovf_edge[OVF_MAX];

// fp32 -> bf16 round-to-nearest-even
__device__ __forceinline__ unsigned short f2bf(float f) {
    unsigned u = __float_as_uint(f);
    unsigned r = u + 0x7fffu + ((u >> 16) & 1u);
    return (unsigned short)(r >> 16);
}

// ------------------------------------------ setup: W^T bf16 + zero cursors
__global__ void setup_kernel(const float* __restrict__ W) {
    const int tid = threadIdx.x;
    if (blockIdx.x < 64) {                  // wt convert: 64 blocks x 4 k's
        int k0 = blockIdx.x * 4;
        #pragma unroll
        for (int j = 0; j < 4; ++j) {
            int k = k0 + j;
            g_wt[(size_t)tid * D + k] = f2bf(W[(size_t)k * D + tid]);
        }
    }
    for (int i = blockIdx.x * blockDim.x + tid; i < N_NODES;
         i += gridDim.x * blockDim.x)
        g_cursor[i] = 0;
    if (blockIdx.x == 0 && tid == 0) g_novf = 0;
}

// ------------------------------------- fused: MFMA GEMM  ||  padded scatter
// blocks [0, GEMM_BLOCKS):         support = bf16(x @ W), inline fp32->bf16
// blocks [GEMM_BLOCKS, +SCAT):     scatter edges into padded CSR
__launch_bounds__(256)
__global__ void gemm_scatter_kernel(const float* __restrict__ x,
                                    const float* __restrict__ edge_val,
                                    const int* __restrict__ edge_row,
                                    const int* __restrict__ edge_col) {
    __shared__ float tile[4][16][68];
    const int tid = threadIdx.x;

    if (blockIdx.x < GEMM_BLOCKS) {
        // ---------------- GEMM part: per-wave 16x64 tile, K=256
        const int wave = tid >> 6;
        const int lane = tid & 63;
        const int m0   = blockIdx.x * 16;
        const int n0   = wave * 64;
        const int lm   = lane & 15;
        const int q    = lane >> 4;

        const unsigned short* B = g_wt;
        f32x4 acc0 = {}, acc1 = {}, acc2 = {}, acc3 = {};

        #pragma unroll
        for (int k0 = 0; k0 < D; k0 += 32) {
            // A frag: read fp32 x, convert inline (RNE)
            const float* Arow = &x[(size_t)(m0 + lm) * D + k0 + q * 8];
            float4 f0 = *(const float4*)&Arow[0];
            float4 f1 = *(const float4*)&Arow[4];
            union { bf16x8 v; unsigned short u[8]; } au;
            au.u[0] = f2bf(f0.x); au.u[1] = f2bf(f0.y);
            au.u[2] = f2bf(f0.z); au.u[3] = f2bf(f0.w);
            au.u[4] = f2bf(f1.x); au.u[5] = f2bf(f1.y);
            au.u[6] = f2bf(f1.z); au.u[7] = f2bf(f1.w);

            bf16x8 b0 = *(const bf16x8*)&B[(size_t)(n0 +  0 + lm) * D + k0 + q * 8];
            bf16x8 b1 = *(const bf16x8*)&B[(size_t)(n0 + 16 + lm) * D + k0 + q * 8];
            bf16x8 b2 = *(const bf16x8*)&B[(size_t)(n0 + 32 + lm) * D + k0 + q * 8];
            bf16x8 b3 = *(const bf16x8*)&B[(size_t)(n0 + 48 + lm) * D + k0 + q * 8];
            acc0 = __builtin_amdgcn_mfma_f32_16x16x32_bf16(au.v, b0, acc0, 0, 0, 0);
            acc1 = __builtin_amdgcn_mfma_f32_16x16x32_bf16(au.v, b1, acc1, 0, 0, 0);
            acc2 = __builtin_amdgcn_mfma_f32_16x16x32_bf16(au.v, b2, acc2, 0, 0, 0);
            acc3 = __builtin_amdgcn_mfma_f32_16x16x32_bf16(au.v, b3, acc3, 0, 0, 0);
        }

        // epilogue: C/D layout col=lane&15, row=q*4+reg — stage through LDS
        #pragma unroll
        for (int r = 0; r < 4; ++r) {
            tile[wave][q * 4 + r][ 0 + lm] = acc0[r];
            tile[wave][q * 4 + r][16 + lm] = acc1[r];
            tile[wave][q * 4 + r][32 + lm] = acc2[r];
            tile[wave][q * 4 + r][48 + lm] = acc3[r];
        }
        // same wave produces & consumes — lgkmcnt ordering suffices
        const int row  = lane >> 2;
        const int cseg = (lane & 3) * 16;
        unsigned short outv[16];
        #pragma unroll
        for (int j = 0; j < 16; ++j)
            outv[j] = f2bf(tile[wave][row][cseg + j]);
        unsigned short* dst = &g_support[(size_t)(m0 + row) * D + n0 + cseg];
        *(uint4*)&dst[0] = *(const uint4*)&outv[0];
        *(uint4*)&dst[8] = *(const uint4*)&outv[8];
    } else {
        // ---------------- scatter part: padded-CSR build
        const int b = blockIdx.x - GEMM_BLOCKS;
        for (int e = b * 256 + tid; e < N_EDGES; e += SCAT_BLOCKS * 256) {
            int r = edge_row[e];
            int slot = atomicAdd(&g_cursor[r], 1);
            int2 pk;
            pk.x = edge_col[e];
            pk.y = __float_as_int(edge_val[e]);
            if (slot < CAP) {
                g_pad[(size_t)r * CAP + slot] = pk;
            } else {
                int o = atomicAdd(&g_novf, 1);
                if (o < OVF_MAX) { g_ovf_row[o] = r; g_ovf_edge[o] = pk; }
            }
        }
    }
}

// ---------------------------------------------------------------- SpMM
// One 128-thread block per row; thread t owns features 2t, 2t+1.
// NT on pad reads (read-once) and out writes (write-once) to keep
// g_support resident in L2 for the gathers.
__launch_bounds__(128)
__global__ void spmm_kernel(float* __restrict__ out) {
    const int r = blockIdx.x;
    const int t = threadIdx.x;
    const int deg = g_cursor[r];
    const int dpad = min(deg, CAP);
    const long long* rowp = (const long long*)&g_pad[(size_t)r * CAP];
    const unsigned* sup = (const unsigned*)g_support;

    float a0 = 0.f, a1 = 0.f;
    int i = 0;
    for (; i + 3 < dpad; i += 4) {
        long long q0 = __builtin_nontemporal_load(&rowp[i]);
        long long q1 = __builtin_nontemporal_load(&rowp[i + 1]);
        long long q2 = __builtin_nontemporal_load(&rowp[i + 2]);
        long long q3 = __builtin_nontemporal_load(&rowp[i + 3]);
        unsigned p0 = sup[(size_t)(int)q0 * (D / 2) + t];
        unsigned p1 = sup[(size_t)(int)q1 * (D / 2) + t];
        unsigned p2 = sup[(size_t)(int)q2 * (D / 2) + t];
        unsigned p3 = sup[(size_t)(int)q3 * (D / 2) + t];
        float v0 = __int_as_float((int)(q0 >> 32));
        float v1 = __int_as_float((int)(q1 >> 32));
        float v2 = __int_as_float((int)(q2 >> 32));
        float v3 = __int_as_float((int)(q3 >> 32));
        a0 += v0 * __uint_as_float(p0 << 16);
        a1 += v0 * __uint_as_float(p0 & 0xffff0000u);
        a0 += v1 * __uint_as_float(p1 << 16);
        a1 += v1 * __uint_as_float(p1 & 0xffff0000u);
        a0 += v2 * __uint_as_float(p2 << 16);
        a1 += v2 * __uint_as_float(p2 & 0xffff0000u);
        a0 += v3 * __uint_as_float(p3 << 16);
        a1 += v3 * __uint_as_float(p3 & 0xffff0000u);
    }
    for (; i < dpad; ++i) {
        long long q0 = __builtin_nontemporal_load(&rowp[i]);
        float v0 = __int_as_float((int)(q0 >> 32));
        unsigned p0 = sup[(size_t)(int)q0 * (D / 2) + t];
        a0 += v0 * __uint_as_float(p0 << 16);
        a1 += v0 * __uint_as_float(p0 & 0xffff0000u);
    }
    if (deg > CAP) {                       // correctness fallback (empty in practice)
        int novf = min(g_novf, OVF_MAX);
        for (int j = 0; j < novf; ++j) {
            if (g_ovf_row[j] == r) {
                int2 e0 = g_ovf_edge[j];
                float v0 = __int_as_float(e0.y);
                unsigned p0 = sup[(size_t)e0.x * (D / 2) + t];
                a0 += v0 * __uint_as_float(p0 << 16);
                a1 += v0 * __uint_as_float(p0 & 0xffff0000u);
            }
        }
    }
    f32x2 o;
    o.x = fmaxf(a0, 0.f);
    o.y = fmaxf(a1, 0.f);
    __builtin_nontemporal_store(o, (f32x2*)&out[(size_t)r * D + 2 * t]);
}

// ---------------------------------------------------------------- launcher
extern "C" void kernel_launch(void* const* d_in, const int* in_sizes, int n_in,
                              void* d_out, int out_size, void* d_ws, size_t ws_size,
                              hipStream_t stream) {
    const float* x        = (const float*)d_in[0];
    const float* weight   = (const float*)d_in[1];
    const float* edge_val = (const float*)d_in[2];
    const int*   edge_row = (const int*)d_in[3];
    const int*   edge_col = (const int*)d_in[4];
    float* out = (float*)d_out;

    setup_kernel<<<160, 256, 0, stream>>>(weight);
    gemm_scatter_kernel<<<GEMM_BLOCKS + SCAT_BLOCKS, 256, 0, stream>>>(
        x, edge_val, edge_row, edge_col);
    spmm_kernel<<<N_NODES, 128, 0, stream>>>(out);
}